// Round 2
// baseline (2691.841 us; speedup 1.0000x reference)
//
#include <hip/hip_runtime.h>

#define T_LEN 2500
#define B_SZ  128
#define I_SZ  76
#define HID   32
#define G3    96   // 3*HID

// ---------------------------------------------------------------------------
// Kernel 1: xg[dir][b][t][g] = dot(X[b,t,:], W_ih[dir][g,:]) + b_ih[dir][g]
// grid: 1250 blocks x 256 threads, thread = (b,t)   (unchanged from R0)
// ---------------------------------------------------------------------------
__global__ __launch_bounds__(256) void xg_kernel(
    const float* __restrict__ X,
    const float* __restrict__ Wf, const float* __restrict__ bf,
    const float* __restrict__ Wb, const float* __restrict__ bb,
    float* __restrict__ xg)
{
    __shared__ __align__(16) float w[2 * G3 * I_SZ + 2 * G3];
    for (int i = threadIdx.x; i < G3 * I_SZ; i += 256) {
        w[i]               = Wf[i];
        w[G3 * I_SZ + i]   = Wb[i];
    }
    for (int i = threadIdx.x; i < G3; i += 256) {
        w[2 * G3 * I_SZ + i]      = bf[i];
        w[2 * G3 * I_SZ + G3 + i] = bb[i];
    }
    __syncthreads();

    const int tid = blockIdx.x * 256 + threadIdx.x;   // 0..319999
    const int b   = tid / T_LEN;
    const int t   = tid - b * T_LEN;

    float x[I_SZ];
    const float4* xr4 = (const float4*)(X + (size_t)b * T_LEN * I_SZ + (size_t)t * I_SZ);
    #pragma unroll
    for (int i = 0; i < I_SZ / 4; ++i) {
        float4 v = xr4[i];
        x[4*i+0] = v.x; x[4*i+1] = v.y; x[4*i+2] = v.z; x[4*i+3] = v.w;
    }

    #pragma unroll 1
    for (int dir = 0; dir < 2; ++dir) {
        const float4* wd = (const float4*)(w + dir * G3 * I_SZ);
        const float*  bd = w + 2 * G3 * I_SZ + dir * G3;
        float* out = xg + (((size_t)dir * B_SZ + b) * T_LEN + t) * G3;

        #pragma unroll 1
        for (int g0 = 0; g0 < G3; g0 += 4) {
            float a0 = bd[g0+0], a1 = bd[g0+1], a2 = bd[g0+2], a3 = bd[g0+3];
            #pragma unroll
            for (int i4 = 0; i4 < I_SZ / 4; ++i4) {
                float4 w0 = wd[(g0+0) * (I_SZ/4) + i4];
                float4 w1 = wd[(g0+1) * (I_SZ/4) + i4];
                float4 w2 = wd[(g0+2) * (I_SZ/4) + i4];
                float4 w3 = wd[(g0+3) * (I_SZ/4) + i4];
                a0 = fmaf(x[4*i4+0], w0.x, a0); a0 = fmaf(x[4*i4+1], w0.y, a0);
                a0 = fmaf(x[4*i4+2], w0.z, a0); a0 = fmaf(x[4*i4+3], w0.w, a0);
                a1 = fmaf(x[4*i4+0], w1.x, a1); a1 = fmaf(x[4*i4+1], w1.y, a1);
                a1 = fmaf(x[4*i4+2], w1.z, a1); a1 = fmaf(x[4*i4+3], w1.w, a1);
                a2 = fmaf(x[4*i4+0], w2.x, a2); a2 = fmaf(x[4*i4+1], w2.y, a2);
                a2 = fmaf(x[4*i4+2], w2.z, a2); a2 = fmaf(x[4*i4+3], w2.w, a2);
                a3 = fmaf(x[4*i4+0], w3.x, a3); a3 = fmaf(x[4*i4+1], w3.y, a3);
                a3 = fmaf(x[4*i4+2], w3.z, a3); a3 = fmaf(x[4*i4+3], w3.w, a3);
            }
            float4 o; o.x = a0; o.y = a1; o.z = a2; o.w = a3;
            *(float4*)(out + g0) = o;
        }
    }
}

// ---------------------------------------------------------------------------
// Kernel 2: sequential GRU scan, zero LDS on the critical path.
// One wave per (b,dir). h state lives in 32 SGPRs (wave-uniform) via readlane.
// lane k  (0..31):  owns gate r_k and n_k (W_r row k, W_n row k in VGPRs)
// lane 32+k:        owns gate z_k (W_z row k; W_n row dup, result unused)
// grid: 256 blocks x 64 threads
// ---------------------------------------------------------------------------
#define PFD 8   // prefetch ring depth (power of 2, matches unroll)

__global__ __launch_bounds__(64) void scan_kernel(
    const float* __restrict__ xg,
    const float* __restrict__ Whf, const float* __restrict__ bhf,
    const float* __restrict__ Whb, const float* __restrict__ bhb,
    float* __restrict__ out)
{
    const int l  = threadIdx.x;
    const int k  = l & 31;
    const int lo = (l < 32);
    const int p  = blockIdx.x;       // pair index 0..255
    const int dir = p >> 7;
    const int b   = p & 127;

    const float* Wh = dir ? Whb : Whf;
    const float* bh = dir ? bhb : bhf;

    // W1: row for dot1 -> lo lanes: W_r[k], hi lanes: W_z[k]
    // W2: row for dot2 -> W_n[k] on both halves
    float w1[HID], w2[HID];
    {
        const int g1row = (lo ? 0 : HID) + k;       // r or z row
        const float4* q1 = (const float4*)(Wh + g1row * HID);
        const float4* q2 = (const float4*)(Wh + (2 * HID + k) * HID);
        #pragma unroll
        for (int i = 0; i < HID / 4; ++i) {
            float4 v = q1[i];
            w1[4*i+0]=v.x; w1[4*i+1]=v.y; w1[4*i+2]=v.z; w1[4*i+3]=v.w;
            float4 u = q2[i];
            w2[4*i+0]=u.x; w2[4*i+1]=u.y; w2[4*i+2]=u.z; w2[4*i+3]=u.w;
        }
    }
    const float b1 = bh[(lo ? 0 : HID) + k];   // b_r or b_z
    const float b2 = bh[2 * HID + k];          // b_n

    // xg stream for this pair; backward walks t downward
    const float* xbase = xg + ((size_t)p * T_LEN + (dir ? (T_LEN - 1) : 0)) * G3;
    const int step = dir ? -G3 : G3;

    // h state: wave-uniform -> SGPRs
    float hs[HID];
    #pragma unroll
    for (int j = 0; j < HID; ++j) hs[j] = 0.f;
    float hk = 0.f;   // lane-private own h (valid in lo lanes)

    // prefetch ring: p1 = xg[t][l] (xr for lo / xz for hi), p2 = xg[t][64 + k] (xn)
    float p1[PFD], p2[PFD];
    #pragma unroll
    for (int d = 0; d < PFD; ++d) {
        const float* q = xbase + (long)d * step;
        p1[d] = q[l];
        p2[d] = q[64 + k];
    }

    #pragma unroll PFD
    for (int t = 0; t < T_LEN; ++t) {
        const int slot = t & (PFD - 1);
        const float x1 = p1[slot];     // lo: xr, hi: xz
        const float xn = p2[slot];
        if (t + PFD < T_LEN) {
            const float* q = xbase + (long)(t + PFD) * step;
            p1[slot] = q[l];
            p2[slot] = q[64 + k];
        }

        // full 32-length dots: VGPR weight x SGPR h (two chains interleave)
        float d1 = b1, d2 = b2;
        #pragma unroll
        for (int j = 0; j < HID; ++j) {
            d1 = fmaf(w1[j], hs[j], d1);
            d2 = fmaf(w2[j], hs[j], d2);
        }

        // shared sigmoid: lo lanes -> r, hi lanes -> z
        float s1 = __builtin_amdgcn_rcpf(
            1.f + __builtin_amdgcn_exp2f(-1.442695040888963f * (x1 + d1)));

        // bring z (hi half of s1) down to lo lanes via VALU permlane swap
        float zk = 0.f;
        {
            float a = s1;
            asm("v_permlane32_swap_b32 %0, %1" : "+v"(a), "+v"(zk));
            // zk[0:31] = s1_old[32:63] = z_k ; s1 lo half unchanged in a
        }

        // n = tanh(xn + r*hn)  (lo lanes; hi lanes compute garbage, unused)
        float a2 = fmaf(s1, d2, xn);
        a2 = fminf(15.f, fmaxf(-15.f, a2));
        const float E = __builtin_amdgcn_exp2f(2.885390081777927f * a2);
        const float n = (E - 1.f) * __builtin_amdgcn_rcpf(E + 1.f);

        // h_new = n + z*(h - n)
        hk = fmaf(zk, hk - n, n);

        // broadcast h_new back to wave-uniform SGPRs (lanes 0..31 hold h)
        #pragma unroll
        for (int j = 0; j < HID; ++j)
            hs[j] = __builtin_bit_cast(float,
                        __builtin_amdgcn_readlane(__builtin_bit_cast(int, hk), j));
    }

    // output: (B, 2, H)
    if (lo) out[(b * 2 + dir) * HID + k] = hk;
}

extern "C" void kernel_launch(void* const* d_in, const int* in_sizes, int n_in,
                              void* d_out, int out_size, void* d_ws, size_t ws_size,
                              hipStream_t stream) {
    const float* X    = (const float*)d_in[0];
    const float* Wihf = (const float*)d_in[1];
    const float* Whhf = (const float*)d_in[2];
    const float* bihf = (const float*)d_in[3];
    const float* bhhf = (const float*)d_in[4];
    const float* Wihb = (const float*)d_in[5];
    const float* Whhb = (const float*)d_in[6];
    const float* bihb = (const float*)d_in[7];
    const float* bhhb = (const float*)d_in[8];
    float* out = (float*)d_out;
    float* xg  = (float*)d_ws;

    const size_t needed = (size_t)2 * B_SZ * T_LEN * G3 * sizeof(float); // 245.76 MB
    if (ws_size < needed) return;

    xg_kernel<<<(B_SZ * T_LEN) / 256, 256, 0, stream>>>(X, Wihf, bihf, Wihb, bihb, xg);
    scan_kernel<<<256, 64, 0, stream>>>(xg, Whhf, bhhf, Whhb, bhhb, out);
}

// Round 3
// 1018.965 us; speedup vs baseline: 2.6417x; 2.6417x over previous
//
#include <hip/hip_runtime.h>

#define T_LEN 2500
#define B_SZ  128
#define I_SZ  76
#define HID   32
#define G3    96   // 3*HID

// ---------------------------------------------------------------------------
// Kernel 1: xg[dir][b][t][g] = dot(X[b,t,:], W_ih[dir][g,:]) + b_ih[dir][g]
// grid: 1250 blocks x 256 threads, thread = (b,t)   (unchanged from R0)
// ---------------------------------------------------------------------------
__global__ __launch_bounds__(256) void xg_kernel(
    const float* __restrict__ X,
    const float* __restrict__ Wf, const float* __restrict__ bf,
    const float* __restrict__ Wb, const float* __restrict__ bb,
    float* __restrict__ xg)
{
    __shared__ __align__(16) float w[2 * G3 * I_SZ + 2 * G3];
    for (int i = threadIdx.x; i < G3 * I_SZ; i += 256) {
        w[i]               = Wf[i];
        w[G3 * I_SZ + i]   = Wb[i];
    }
    for (int i = threadIdx.x; i < G3; i += 256) {
        w[2 * G3 * I_SZ + i]      = bf[i];
        w[2 * G3 * I_SZ + G3 + i] = bb[i];
    }
    __syncthreads();

    const int tid = blockIdx.x * 256 + threadIdx.x;   // 0..319999
    const int b   = tid / T_LEN;
    const int t   = tid - b * T_LEN;

    float x[I_SZ];
    const float4* xr4 = (const float4*)(X + (size_t)b * T_LEN * I_SZ + (size_t)t * I_SZ);
    #pragma unroll
    for (int i = 0; i < I_SZ / 4; ++i) {
        float4 v = xr4[i];
        x[4*i+0] = v.x; x[4*i+1] = v.y; x[4*i+2] = v.z; x[4*i+3] = v.w;
    }

    #pragma unroll 1
    for (int dir = 0; dir < 2; ++dir) {
        const float4* wd = (const float4*)(w + dir * G3 * I_SZ);
        const float*  bd = w + 2 * G3 * I_SZ + dir * G3;
        float* out = xg + (((size_t)dir * B_SZ + b) * T_LEN + t) * G3;

        #pragma unroll 1
        for (int g0 = 0; g0 < G3; g0 += 4) {
            float a0 = bd[g0+0], a1 = bd[g0+1], a2 = bd[g0+2], a3 = bd[g0+3];
            #pragma unroll
            for (int i4 = 0; i4 < I_SZ / 4; ++i4) {
                float4 w0 = wd[(g0+0) * (I_SZ/4) + i4];
                float4 w1 = wd[(g0+1) * (I_SZ/4) + i4];
                float4 w2 = wd[(g0+2) * (I_SZ/4) + i4];
                float4 w3 = wd[(g0+3) * (I_SZ/4) + i4];
                a0 = fmaf(x[4*i4+0], w0.x, a0); a0 = fmaf(x[4*i4+1], w0.y, a0);
                a0 = fmaf(x[4*i4+2], w0.z, a0); a0 = fmaf(x[4*i4+3], w0.w, a0);
                a1 = fmaf(x[4*i4+0], w1.x, a1); a1 = fmaf(x[4*i4+1], w1.y, a1);
                a1 = fmaf(x[4*i4+2], w1.z, a1); a1 = fmaf(x[4*i4+3], w1.w, a1);
                a2 = fmaf(x[4*i4+0], w2.x, a2); a2 = fmaf(x[4*i4+1], w2.y, a2);
                a2 = fmaf(x[4*i4+2], w2.z, a2); a2 = fmaf(x[4*i4+3], w2.w, a2);
                a3 = fmaf(x[4*i4+0], w3.x, a3); a3 = fmaf(x[4*i4+1], w3.y, a3);
                a3 = fmaf(x[4*i4+2], w3.z, a3); a3 = fmaf(x[4*i4+3], w3.w, a3);
            }
            float4 o; o.x = a0; o.y = a1; o.z = a2; o.w = a3;
            *(float4*)(out + g0) = o;
        }
    }
}

// ---------------------------------------------------------------------------
// Kernel 2: sequential GRU scan. One wave per (b,dir) pair.
// lane l: k = l&31 (hidden index), kh = l>>5 (K-half for split dot products)
// R2: branchless clamped prefetch (no control flow in loop -> precise vmcnt),
//     permlane32_swap half-combine (VALU) instead of shfl_xor (ds_bpermute).
// grid: 256 blocks x 64 threads
// ---------------------------------------------------------------------------
#define PFD 4   // prefetch ring depth (power of 2, matches unroll)

__global__ __launch_bounds__(64) void scan_kernel(
    const float* __restrict__ xg,
    const float* __restrict__ Whf, const float* __restrict__ bhf,
    const float* __restrict__ Whb, const float* __restrict__ bhb,
    float* __restrict__ out)
{
    __shared__ __align__(16) float hsh[HID];

    const int l  = threadIdx.x;
    const int k  = l & 31;
    const int kh = l >> 5;
    const int p  = blockIdx.x;       // pair index 0..255
    const int dir = p >> 7;
    const int b   = p & 127;

    const float* Wh = dir ? Whb : Whf;
    const float* bh = dir ? bhb : bhf;

    // per-lane W_hh fragments: rows {k, 32+k, 64+k}, cols [kh*16, kh*16+16)
    float wr[16], wz[16], wn[16];
    {
        const float4* q;
        q = (const float4*)(Wh + (0*HID + k) * HID + kh * 16);
        #pragma unroll
        for (int i = 0; i < 4; ++i) { float4 v = q[i];
            wr[4*i+0]=v.x; wr[4*i+1]=v.y; wr[4*i+2]=v.z; wr[4*i+3]=v.w; }
        q = (const float4*)(Wh + (1*HID + k) * HID + kh * 16);
        #pragma unroll
        for (int i = 0; i < 4; ++i) { float4 v = q[i];
            wz[4*i+0]=v.x; wz[4*i+1]=v.y; wz[4*i+2]=v.z; wz[4*i+3]=v.w; }
        q = (const float4*)(Wh + (2*HID + k) * HID + kh * 16);
        #pragma unroll
        for (int i = 0; i < 4; ++i) { float4 v = q[i];
            wn[4*i+0]=v.x; wn[4*i+1]=v.y; wn[4*i+2]=v.z; wn[4*i+3]=v.w; }
    }
    // half-bias trick: both K-halves contribute bias*0.5, the combine sums to 1x
    const float bhr = 0.5f * bh[k];
    const float bhz = 0.5f * bh[32 + k];
    const float bhn = 0.5f * bh[64 + k];

    // xg stream for this pair; backward walks t downward
    const float* xbase = xg + ((size_t)p * T_LEN + (dir ? (T_LEN - 1) : 0)) * G3;
    const int step = dir ? -G3 : G3;

    float hh[16];
    #pragma unroll
    for (int j = 0; j < 16; ++j) hh[j] = 0.f;
    float hk = 0.f;

    // PFD-deep prefetch ring (statically indexed via unroll)
    float px[PFD], py[PFD], pz[PFD];
    #pragma unroll
    for (int d = 0; d < PFD; ++d) {
        const float* q = xbase + (long)d * step;
        px[d] = q[k]; py[d] = q[32 + k]; pz[d] = q[64 + k];
    }

    #pragma unroll PFD
    for (int t = 0; t < T_LEN; ++t) {
        const int slot = t & (PFD - 1);
        const float xr = px[slot], xz = py[slot], xn = pz[slot];

        // branchless clamped prefetch: uniform SALU select, no control flow,
        // so the compiler can track vmcnt precisely (ring slack = PFD steps)
        {
            const int tp = (t + PFD < T_LEN) ? (t + PFD) : (T_LEN - 1);
            const float* q = xbase + (long)tp * step;
            px[slot] = q[k]; py[slot] = q[32 + k]; pz[slot] = q[64 + k];
        }

        // partial dots over this lane's K-half (3 chains of 16, interleaved)
        float hr = bhr, hz = bhz, hn = bhn;
        #pragma unroll
        for (int j = 0; j < 16; ++j) {
            hr = fmaf(wr[j], hh[j], hr);
            hz = fmaf(wz[j], hh[j], hz);
            hn = fmaf(wn[j], hh[j], hn);
        }
        // combine K-halves via VALU permlane swap (op0_hi <-> op1_lo):
        // t0 = [lo,lo], t1 = [hi,hi]  ->  sum = lo+hi in all lanes
        {
            float a0 = hr, a1 = hr;
            asm("v_permlane32_swap_b32 %0, %1" : "+v"(a0), "+v"(a1));
            hr = a0 + a1;
            float b0 = hz, b1 = hz;
            asm("v_permlane32_swap_b32 %0, %1" : "+v"(b0), "+v"(b1));
            hz = b0 + b1;
            float c0 = hn, c1 = hn;
            asm("v_permlane32_swap_b32 %0, %1" : "+v"(c0), "+v"(c1));
            hn = c0 + c1;
        }

        const float r = __builtin_amdgcn_rcpf(
            1.f + __builtin_amdgcn_exp2f(-1.442695040888963f * (xr + hr)));
        const float z = __builtin_amdgcn_rcpf(
            1.f + __builtin_amdgcn_exp2f(-1.442695040888963f * (xz + hz)));
        float a = fmaf(r, hn, xn);
        a = fminf(15.f, fmaxf(-15.f, a));
        const float E = __builtin_amdgcn_exp2f(2.885390081777927f * a);
        const float n = (E - 1.f) * __builtin_amdgcn_rcpf(E + 1.f);
        hk = fmaf(z, hk - n, n);

        // broadcast h_new: lanes l and l+32 write identical values to hsh[k];
        // single-wave block, in-order LDS pipe => no barrier needed
        hsh[k] = hk;
        const float4* hv = (const float4*)(hsh + kh * 16);
        float4 h0 = hv[0], h1 = hv[1], h2 = hv[2], h3 = hv[3];
        hh[ 0]=h0.x; hh[ 1]=h0.y; hh[ 2]=h0.z; hh[ 3]=h0.w;
        hh[ 4]=h1.x; hh[ 5]=h1.y; hh[ 6]=h1.z; hh[ 7]=h1.w;
        hh[ 8]=h2.x; hh[ 9]=h2.y; hh[10]=h2.z; hh[11]=h2.w;
        hh[12]=h3.x; hh[13]=h3.y; hh[14]=h3.z; hh[15]=h3.w;
    }

    // output: (B, 2, H)
    if (l < 32) out[(b * 2 + dir) * HID + k] = hk;
}

extern "C" void kernel_launch(void* const* d_in, const int* in_sizes, int n_in,
                              void* d_out, int out_size, void* d_ws, size_t ws_size,
                              hipStream_t stream) {
    const float* X    = (const float*)d_in[0];
    const float* Wihf = (const float*)d_in[1];
    const float* Whhf = (const float*)d_in[2];
    const float* bihf = (const float*)d_in[3];
    const float* bhhf = (const float*)d_in[4];
    const float* Wihb = (const float*)d_in[5];
    const float* Whhb = (const float*)d_in[6];
    const float* bihb = (const float*)d_in[7];
    const float* bhhb = (const float*)d_in[8];
    float* out = (float*)d_out;
    float* xg  = (float*)d_ws;

    const size_t needed = (size_t)2 * B_SZ * T_LEN * G3 * sizeof(float); // 245.76 MB
    if (ws_size < needed) return;

    xg_kernel<<<(B_SZ * T_LEN) / 256, 256, 0, stream>>>(X, Wihf, bihf, Wihb, bihb, xg);
    scan_kernel<<<256, 64, 0, stream>>>(xg, Whhf, bhhf, Whhb, bhhb, out);
}